// Round 1
// baseline (6973.219 us; speedup 1.0000x reference)
//
#include <hip/hip_runtime.h>
#include <math.h>

#define Dz 16
#define Hy 64
#define Wx 64
#define CHN 256
#define NVOX (Dz*Hy*Wx)      // 65536
#define TOPK 2048
#define MAXOUT 256
#define CAND_CAP 4096

__device__ __forceinline__ float gelu_tanh(float x) {
    return 0.5f*x*(1.0f + tanhf(0.7978845608028654f*(x + 0.044715f*x*x*x)));
}
__device__ __forceinline__ unsigned f2sort(float f) {
    unsigned u = __float_as_uint(f);
    return (u & 0x80000000u) ? ~u : (u | 0x80000000u);
}
__device__ __forceinline__ float sort2f(unsigned s) {
    unsigned u = (s & 0x80000000u) ? (s & 0x7fffffffu) : ~s;
    return __uint_as_float(u);
}

// 3x3x3 SAME conv for one (z,y) row: 64 x-positions x 256 out-channels.
// Thread: cog = tid&31 -> co = cog*8..+7 ; xg = tid>>5 -> x = xg*8..+7
// (wave = 32 cog x 2 xg -> LDS activation reads are 2-address broadcast = free)
__device__ __forceinline__ void conv_row_acc(const float* __restrict__ in,
                                             const float* __restrict__ w,
                                             float4* __restrict__ lds4,
                                             int z, int y, int cog, int xg, int tid,
                                             float acc[8][8]) {
    for (int dz = 0; dz < 3; ++dz) {
        for (int dy = 0; dy < 3; ++dy) {
            int zz = z + dz - 1, yy = y + dy - 1;
            bool rowok = ((unsigned)zz < (unsigned)Dz) && ((unsigned)yy < (unsigned)Hy);
            __syncthreads();   // protect LDS from previous tap's readers
            for (int idx = tid; idx < 66*64; idx += 256) {
                int xi = idx >> 6, c4 = idx & 63, x = xi - 1;
                float4 v = make_float4(0.f, 0.f, 0.f, 0.f);
                if (rowok && (unsigned)x < (unsigned)Wx) {
                    const float* src = in + ((((long long)zz*Hy + yy)*Wx + x))*CHN + (c4 << 2);
                    v = *(const float4*)src;
                }
                lds4[idx] = v;
            }
            __syncthreads();
            for (int dx = 0; dx < 3; ++dx) {
                const float* wb = w + ((size_t)((dz*3+dy)*3+dx))*CHN*CHN + cog*8;
                for (int c4 = 0; c4 < 64; ++c4) {
                    float4 a[8];
                    #pragma unroll
                    for (int i = 0; i < 8; ++i)
                        a[i] = lds4[(xg*8 + i + dx)*64 + c4];
                    #pragma unroll
                    for (int q = 0; q < 4; ++q) {
                        const float* wr = wb + (size_t)(c4*4 + q)*CHN;
                        float4 wa = *(const float4*)(wr);
                        float4 wc = *(const float4*)(wr + 4);
                        #pragma unroll
                        for (int i = 0; i < 8; ++i) {
                            float av = (q==0)?a[i].x:(q==1)?a[i].y:(q==2)?a[i].z:a[i].w;
                            acc[i][0] += av*wa.x; acc[i][1] += av*wa.y;
                            acc[i][2] += av*wa.z; acc[i][3] += av*wa.w;
                            acc[i][4] += av*wc.x; acc[i][5] += av*wc.y;
                            acc[i][6] += av*wc.z; acc[i][7] += av*wc.w;
                        }
                    }
                }
            }
        }
    }
}

__global__ __launch_bounds__(256) void conv1_kernel(const float* __restrict__ in,
        const float* __restrict__ w, const float* __restrict__ bias,
        float* __restrict__ out) {
    __shared__ float4 lds4[66*64];
    int y = blockIdx.x, z = blockIdx.y;
    int tid = threadIdx.x, cog = tid & 31, xg = tid >> 5;
    float acc[8][8];
    #pragma unroll
    for (int i = 0; i < 8; ++i)
        #pragma unroll
        for (int k = 0; k < 8; ++k) acc[i][k] = 0.f;
    conv_row_acc(in, w, lds4, z, y, cog, xg, tid, acc);
    float b[8];
    #pragma unroll
    for (int k = 0; k < 8; ++k) b[k] = bias[cog*8 + k];
    #pragma unroll
    for (int i = 0; i < 8; ++i) {
        float* op = out + ((size_t)(z*Hy + y)*Wx + xg*8 + i)*CHN + cog*8;
        float4 o0, o1;
        o0.x = gelu_tanh(acc[i][0]+b[0]); o0.y = gelu_tanh(acc[i][1]+b[1]);
        o0.z = gelu_tanh(acc[i][2]+b[2]); o0.w = gelu_tanh(acc[i][3]+b[3]);
        o1.x = gelu_tanh(acc[i][4]+b[4]); o1.y = gelu_tanh(acc[i][5]+b[5]);
        o1.z = gelu_tanh(acc[i][6]+b[6]); o1.w = gelu_tanh(acc[i][7]+b[7]);
        *(float4*)op = o0; *(float4*)(op + 4) = o1;
    }
}

__global__ __launch_bounds__(256) void conv2_det_kernel(const float* __restrict__ h1,
        const float* __restrict__ w, const float* __restrict__ bias,
        const float* __restrict__ wlog, const float* __restrict__ blog,
        const float* __restrict__ wreg, const float* __restrict__ breg,
        float* __restrict__ locs, unsigned long long* __restrict__ keys,
        unsigned* __restrict__ hist) {
    __shared__ float4 lds4[66*64];
    float* lds = (float*)lds4;
    int y = blockIdx.x, z = blockIdx.y;
    int tid = threadIdx.x, cog = tid & 31, xg = tid >> 5;
    float acc[8][8];
    #pragma unroll
    for (int i = 0; i < 8; ++i)
        #pragma unroll
        for (int k = 0; k < 8; ++k) acc[i][k] = 0.f;
    conv_row_acc(h1, w, lds4, z, y, cog, xg, tid, acc);
    float b[8];
    #pragma unroll
    for (int k = 0; k < 8; ++k) b[k] = bias[cog*8 + k];
    __syncthreads();   // done reading input row LDS; reuse as activation tile
    #pragma unroll
    for (int i = 0; i < 8; ++i) {
        int x = xg*8 + i;
        #pragma unroll
        for (int k = 0; k < 8; ++k)
            lds[x*CHN + cog*8 + k] = gelu_tanh(acc[i][k] + b[k]);
    }
    __syncthreads();
    // detection head: 4 threads per voxel -> (logit, reg0, reg1, reg2)
    int vox = tid >> 2, chn = tid & 3;
    const float* tp = lds + vox*CHN;
    float dot = 0.f;
    if (chn == 0) {
        for (int c = 0; c < CHN; ++c) dot += tp[c]*wlog[c];
    } else {
        for (int c = 0; c < CHN; ++c) dot += tp[c]*wreg[c*3 + (chn-1)];
    }
    int vg = (z*Hy + y)*Wx + vox;
    if (chn == 0) {
        float logit = dot + blog[0];
        float score = 1.f/(1.f + expf(-logit));
        unsigned s = f2sort(score);
        keys[vg] = ((unsigned long long)s << 32) | (unsigned long long)(0xFFFFFFFFu - (unsigned)vg);
        atomicAdd(&hist[s >> 12], 1u);
    } else {
        float coord = (chn == 1) ? (float)z : (chn == 2) ? (float)y : (float)vox;
        float loc = (coord + 0.5f)*4.0f + (dot + breg[chn-1])*4.0f;
        locs[(size_t)vg*3 + (chn-1)] = loc;
    }
}

__global__ void zero_kernel(unsigned* __restrict__ hist, unsigned* __restrict__ counter) {
    int i = blockIdx.x*blockDim.x + threadIdx.x;
    if (i < (1 << 20)) hist[i] = 0u;
    if (i == 0) counter[0] = 0u;
}

__global__ __launch_bounds__(1024) void find_cut_kernel(const unsigned* __restrict__ hist,
                                                        unsigned* __restrict__ cutp) {
    __shared__ unsigned long long psum[1024];
    __shared__ unsigned h2[1024];
    __shared__ int sh_cb;
    __shared__ unsigned long long sh_acc;
    int t = threadIdx.x;
    unsigned long long s = 0;
    const unsigned* hp = hist + (size_t)t*1024;
    for (int b = 0; b < 1024; ++b) s += hp[b];
    psum[t] = s;
    __syncthreads();
    if (t == 0) {
        unsigned long long acc = 0; int cb = 0;
        for (int c = 1023; c >= 0; --c) {
            if (acc + psum[c] >= TOPK) { cb = c; break; }
            acc += psum[c];
        }
        sh_cb = cb; sh_acc = acc;
    }
    __syncthreads();
    int cb = sh_cb;
    h2[t] = hist[(size_t)cb*1024 + t];
    __syncthreads();
    if (t == 0) {
        unsigned long long acc = sh_acc; int cut = cb*1024;
        for (int b = 1023; b >= 0; --b) {
            acc += h2[b];
            if (acc >= TOPK) { cut = cb*1024 + b; break; }
        }
        cutp[0] = ((unsigned)cut) << 12;   // threshold on sortable score bits
    }
}

__global__ void compact_kernel(const unsigned long long* __restrict__ keys,
                               const unsigned* __restrict__ cutp,
                               unsigned* __restrict__ counter,
                               unsigned long long* __restrict__ cand) {
    int i = blockIdx.x*blockDim.x + threadIdx.x;
    unsigned thr = cutp[0];
    unsigned long long k = keys[i];
    if ((unsigned)(k >> 32) >= thr) {
        unsigned p = atomicAdd(counter, 1u);
        if (p < CAND_CAP) cand[p] = k;
    }
}

__global__ __launch_bounds__(512) void sort_nms_kernel(const unsigned* __restrict__ counter,
        const unsigned long long* __restrict__ cand,
        const float* __restrict__ locs, const int* __restrict__ mask,
        float* __restrict__ out) {
    __shared__ unsigned long long skey[CAND_CAP];   // 32 KB, later reused: sloc(24K)+scanB(8K)
    __shared__ float sscore[TOPK];
    __shared__ unsigned sidx[TOPK];
    __shared__ unsigned char keepf[TOPK];
    __shared__ unsigned char supf[TOPK];
    __shared__ int scanA[TOPK];
    int t = threadIdx.x;
    int M = (int)*counter; if (M > CAND_CAP) M = CAND_CAP;
    for (int i = t; i < CAND_CAP; i += 512) skey[i] = (i < M) ? cand[i] : 0ull;
    __syncthreads();
    // bitonic sort, descending (keys unique -> deterministic)
    for (int k = 2; k <= CAND_CAP; k <<= 1) {
        for (int j = k >> 1; j > 0; j >>= 1) {
            for (int i = t; i < CAND_CAP; i += 512) {
                int l = i ^ j;
                if (l > i) {
                    unsigned long long a = skey[i], bb = skey[l];
                    bool sw = ((i & k) == 0) ? (a < bb) : (a > bb);
                    if (sw) { skey[i] = bb; skey[l] = a; }
                }
            }
            __syncthreads();
        }
    }
    for (int i = t; i < TOPK; i += 512) {
        unsigned long long kk = skey[i];
        sscore[i] = sort2f((unsigned)(kk >> 32));
        sidx[i] = 0xFFFFFFFFu - (unsigned)(kk & 0xFFFFFFFFull);
        supf[i] = 0;
    }
    __syncthreads();
    float* sloc = (float*)skey;   // reuse (extraction complete)
    for (int i = t; i < TOPK; i += 512) {
        unsigned v = sidx[i];
        sloc[i*3+0] = locs[(size_t)v*3+0];
        sloc[i*3+1] = locs[(size_t)v*3+1];
        sloc[i*3+2] = locs[(size_t)v*3+2];
    }
    __syncthreads();
    // greedy sequential NMS (matches jax scan semantics)
    for (int i = 0; i < TOPK; ++i) {
        bool kept = (supf[i] == 0) && (sscore[i] >= 0.2f);
        if (t == 0) keepf[i] = kept ? 1 : 0;
        if (kept) {
            float pz = sloc[i*3+0], py = sloc[i*3+1], px = sloc[i*3+2];
            for (int jj = t; jj < TOPK; jj += 512) {
                float az = sloc[jj*3+0]-pz, ay = sloc[jj*3+1]-py, ax = sloc[jj*3+2]-px;
                if (az*az + ay*ay + ax*ax < 64.0f) supf[jj] = 1;
            }
        }
        __syncthreads();
    }
    // inclusive scan of keep flags
    for (int i = t; i < TOPK; i += 512) scanA[i] = keepf[i];
    __syncthreads();
    int* sB = ((int*)skey) + TOPK*3;   // 8 KB spare after sloc
    for (int off = 1; off < TOPK; off <<= 1) {
        for (int i = t; i < TOPK; i += 512) sB[i] = scanA[i] + ((i >= off) ? scanA[i-off] : 0);
        __syncthreads();
        for (int i = t; i < TOPK; i += 512) scanA[i] = sB[i];
        __syncthreads();
    }
    int nk = scanA[TOPK-1];
    // slot assignment replicating top_k(sel_scores, 256): kept first (already
    // sorted desc), then zero entries by ascending index
    for (int i = t; i < TOPK; i += 512) {
        bool kp = keepf[i] != 0;
        int slot = kp ? (scanA[i] - 1) : (nk + (i + 1 - scanA[i]) - 1);
        if (slot < MAXOUT) {
            float lz = sloc[i*3+0], ly = sloc[i*3+1], lx = sloc[i*3+2];
            float sc = kp ? sscore[i] : 0.f;
            int iz = (int)floorf(lz), iy = (int)floorf(ly), ix = (int)floorf(lx);
            int cz = min(max(iz,0),Dz*4-1), cy = min(max(iy,0),Hy*4-1), cx = min(max(ix,0),Wx*4-1);
            bool inr = (iz==cz) && (iy==cy) && (ix==cx);
            float osc = (inr && mask[((size_t)cz*(Hy*4) + cy)*(Wx*4) + cx] != 0) ? sc : 0.f;
            out[slot*4+0] = lz; out[slot*4+1] = ly; out[slot*4+2] = lx; out[slot*4+3] = osc;
        }
    }
}

extern "C" void kernel_launch(void* const* d_in, const int* in_sizes, int n_in,
                              void* d_out, int out_size, void* d_ws, size_t ws_size,
                              hipStream_t stream) {
    const float* feature = (const float*)d_in[0];
    const int*   mask    = (const int*)d_in[1];
    const float* w0   = (const float*)d_in[2];
    const float* b0   = (const float*)d_in[3];
    const float* w1   = (const float*)d_in[4];
    const float* b1   = (const float*)d_in[5];
    const float* wlog = (const float*)d_in[6];
    const float* blog = (const float*)d_in[7];
    const float* wreg = (const float*)d_in[8];
    const float* breg = (const float*)d_in[9];

    char* ws = (char*)d_ws;
    size_t off = 0;
    float* h1 = (float*)(ws + off);                 off += (size_t)NVOX*CHN*4;      // 64 MB
    unsigned long long* keys = (unsigned long long*)(ws + off); off += (size_t)NVOX*8;
    float* locs = (float*)(ws + off);               off += (size_t)NVOX*3*4;
    unsigned* hist = (unsigned*)(ws + off);         off += (size_t)(1u<<20)*4;      // 4 MB
    unsigned* counter = (unsigned*)(ws + off);      off += 256;
    unsigned* cutp = counter + 1;
    unsigned long long* cand = (unsigned long long*)(ws + off); off += (size_t)CAND_CAP*8;
    if (ws_size < off) return;   // scratch too small: fail loudly (poison output)

    zero_kernel<<<4096, 256, 0, stream>>>(hist, counter);
    dim3 cgrid(Hy, Dz);
    conv1_kernel<<<cgrid, 256, 0, stream>>>(feature, w0, b0, h1);
    conv2_det_kernel<<<cgrid, 256, 0, stream>>>(h1, w1, b1, wlog, blog, wreg, breg,
                                                locs, keys, hist);
    find_cut_kernel<<<1, 1024, 0, stream>>>(hist, cutp);
    compact_kernel<<<NVOX/256, 256, 0, stream>>>(keys, cutp, counter, cand);
    sort_nms_kernel<<<1, 512, 0, stream>>>(counter, cand, locs, mask, (float*)d_out);
}

// Round 2
// 2381.494 us; speedup vs baseline: 2.9281x; 2.9281x over previous
//
#include <hip/hip_runtime.h>
#include <math.h>

#define Dz 16
#define Hy 64
#define Wx 64
#define CHN 256
#define NVOX (Dz*Hy*Wx)      // 65536
#define TOPK 2048
#define MAXOUT 256
#define CAND_CAP 4096

typedef __attribute__((ext_vector_type(8))) _Float16 h8;
typedef __attribute__((ext_vector_type(8))) unsigned short u16x8;
typedef __attribute__((ext_vector_type(4))) float f32x4;

__device__ __forceinline__ float gelu_tanh(float x) {
    return 0.5f*x*(1.0f + tanhf(0.7978845608028654f*(x + 0.044715f*x*x*x)));
}
__device__ __forceinline__ unsigned f2sort(float f) {
    unsigned u = __float_as_uint(f);
    return (u & 0x80000000u) ? ~u : (u | 0x80000000u);
}
__device__ __forceinline__ float sort2f(unsigned s) {
    unsigned u = (s & 0x80000000u) ? (s & 0x7fffffffu) : ~s;
    return __uint_as_float(u);
}

#define MFMA(d, a, b) d = __builtin_amdgcn_mfma_f32_16x16x32_f16(a, b, d, 0, 0, 0)

// ---------------------------------------------------------------------------
// Weight pre-pack: w[tap][k][co] f32 -> per-lane MFMA B-fragment order, f16
// hi/lo planes. Chunk (16B) = (((tap*8+kbg)*16 + ng)*2 + plane)*64 + lane,
// holding B[k = kbg*32 + (lane>>4)*8 + j][co = ng*16 + (lane&15)], j=0..7.
// ---------------------------------------------------------------------------
__global__ __launch_bounds__(256) void pack_w_kernel(const float* __restrict__ w0,
        const float* __restrict__ w1, u16x8* __restrict__ wpk0,
        u16x8* __restrict__ wpk1) {
    int id = blockIdx.x*256 + threadIdx.x;        // 442368 total
    int l = (id >= 221184) ? 1 : 0;
    int r = id - l*221184;
    int lane = r & 63, ng = (r >> 6) & 15, kbg = (r >> 10) & 7, t = r >> 13; // t 0..26
    const float* w = l ? w1 : w0;
    u16x8* dst = l ? wpk1 : wpk0;
    h8 hv = {0,0,0,0,0,0,0,0}, lv = {0,0,0,0,0,0,0,0};
    #pragma unroll
    for (int j = 0; j < 8; ++j) {
        int k = kbg*32 + (lane >> 4)*8 + j;
        int co = ng*16 + (lane & 15);
        float v = w[((size_t)t*CHN + k)*CHN + co];
        _Float16 h = (_Float16)v;
        hv[j] = h;
        lv[j] = (_Float16)(v - (float)h);
    }
    size_t base = (((size_t)(t*8 + kbg)*16 + ng)*2)*64 + lane;
    dst[base]      = __builtin_bit_cast(u16x8, hv);
    dst[base + 64] = __builtin_bit_cast(u16x8, lv);
}

// ---------------------------------------------------------------------------
// Conv layer as MFMA GEMM. Block = (z, y0..y0+1): M=128 voxels, N=256 cos.
// 512 threads = 8 waves: yo = w>>2, wn = w&3 (co 64-range). Wave tile 64x64.
// LDS: [plane2][iy4][row66][chunk8] of 16B f16 chunks, XOR-(r&7) swizzled.
// ---------------------------------------------------------------------------
template<int LAYER>
__global__ __launch_bounds__(512, 4) void conv_kernel(
        const float* __restrict__ fsrc,
        const unsigned short* __restrict__ hhi, const unsigned short* __restrict__ hlo,
        const u16x8* __restrict__ wpk, const float* __restrict__ bias,
        unsigned short* __restrict__ ohi, unsigned short* __restrict__ olo,
        const float* __restrict__ wlog, const float* __restrict__ blog,
        const float* __restrict__ wreg, const float* __restrict__ breg,
        float* __restrict__ locs, unsigned long long* __restrict__ keys,
        unsigned* __restrict__ hist) {
    __shared__ h8 sm[4224];                       // 67584 B
    const int tid = threadIdx.x;
    const int lane = tid & 63, w = tid >> 6;
    const int yo = w >> 2, wn = w & 3;
    const int lr = lane & 15, lg = lane >> 4;
    const int z = blockIdx.y, y0 = blockIdx.x*2;

    f32x4 acc[4][4];
    #pragma unroll
    for (int m = 0; m < 4; ++m)
        #pragma unroll
        for (int n = 0; n < 4; ++n) acc[m][n] = (f32x4){0.f,0.f,0.f,0.f};

    for (int dz = 0; dz < 3; ++dz) {
        const int zz = z + dz - 1;
        for (int kc = 0; kc < 4; ++kc) {
            __syncthreads();
            // ------------- stage 4 in-rows (hi/lo) for this (dz, kc) -------------
            if (LAYER == 0) {
                for (int cidx = tid; cidx < 2112; cidx += 512) {
                    int cd = cidx & 7;
                    int rr = cidx >> 3;
                    int r = rr % 66, iy = rr / 66;
                    int ygl = y0 - 1 + iy, xin = r - 1;
                    h8 hv = {0,0,0,0,0,0,0,0}, lv = {0,0,0,0,0,0,0,0};
                    if (((unsigned)zz < (unsigned)Dz) & ((unsigned)ygl < (unsigned)Hy)
                        & ((unsigned)xin < (unsigned)Wx)) {
                        const float* s = fsrc + ((size_t)((zz*Hy + ygl)*Wx + xin))*CHN
                                              + kc*64 + cd*8;
                        float4 t0 = *(const float4*)s;
                        float4 t1 = *(const float4*)(s + 4);
                        float vv[8] = {t0.x,t0.y,t0.z,t0.w,t1.x,t1.y,t1.z,t1.w};
                        #pragma unroll
                        for (int j = 0; j < 8; ++j) {
                            _Float16 h = (_Float16)vv[j];
                            hv[j] = h;
                            lv[j] = (_Float16)(vv[j] - (float)h);
                        }
                    }
                    int sl = cd ^ (r & 7);
                    sm[(iy*66 + r)*8 + sl] = hv;
                    sm[2112 + (iy*66 + r)*8 + sl] = lv;
                }
            } else {
                for (int cidx = tid; cidx < 4224; cidx += 512) {
                    int c = cidx & 7;
                    int rr = cidx >> 3;
                    int r = rr % 66, tt = rr / 66;     // tt = p*4+iy
                    int p = tt >> 2, iy = tt & 3;
                    int ygl = y0 - 1 + iy, xin = r - 1;
                    u16x8 v = {0,0,0,0,0,0,0,0};
                    if (((unsigned)zz < (unsigned)Dz) & ((unsigned)ygl < (unsigned)Hy)
                        & ((unsigned)xin < (unsigned)Wx)) {
                        const unsigned short* bp = p ? hlo : hhi;
                        v = *(const u16x8*)(bp + ((size_t)((zz*Hy + ygl)*Wx + xin))*CHN
                                               + kc*64 + (size_t)((c ^ (r & 7)))*8);
                    }
                    sm[cidx] = __builtin_bit_cast(h8, v);
                }
            }
            __syncthreads();
            // ------------- compute: 9 (dy,dx) taps x 2 kb -------------
            for (int dy = 0; dy < 3; ++dy) {
                const int iyA = yo + dy;
                const h8* As = sm + iyA*528;
                #pragma unroll
                for (int dx = 0; dx < 3; ++dx) {
                    const int tap = (dz*3 + dy)*3 + dx;
                    #pragma unroll
                    for (int kb = 0; kb < 2; ++kb) {
                        const int kbg = kc*2 + kb;
                        const u16x8* wb = wpk + ((size_t)(tap*8 + kbg)*32 + wn*8)*64 + lane;
                        h8 bh[4];
                        #pragma unroll
                        for (int n = 0; n < 4; ++n)
                            bh[n] = __builtin_bit_cast(h8, wb[(size_t)n*128]);
                        #pragma unroll
                        for (int m = 0; m < 4; ++m) {
                            const int r = m*16 + lr + dx;
                            const int sl = (kb*4 + lg) ^ (r & 7);
                            h8 ah = As[r*8 + sl];
                            h8 al = As[2112 + r*8 + sl];
                            #pragma unroll
                            for (int n = 0; n < 4; ++n) {
                                MFMA(acc[m][n], ah, bh[n]);
                                MFMA(acc[m][n], al, bh[n]);
                            }
                        }
                        h8 bl[4];
                        #pragma unroll
                        for (int n = 0; n < 4; ++n)
                            bl[n] = __builtin_bit_cast(h8, wb[(size_t)n*128 + 64]);
                        #pragma unroll
                        for (int m = 0; m < 4; ++m) {
                            const int r = m*16 + lr + dx;
                            const int sl = (kb*4 + lg) ^ (r & 7);
                            h8 ah = As[r*8 + sl];
                            #pragma unroll
                            for (int n = 0; n < 4; ++n) MFMA(acc[m][n], ah, bl[n]);
                        }
                    }
                }
            }
        }
    }

    // ------------------------------ epilogue ------------------------------
    float bn[4];
    #pragma unroll
    for (int n = 0; n < 4; ++n) bn[n] = bias[wn*64 + n*16 + lr];

    if (LAYER == 0) {
        const int ygl = y0 + yo;
        #pragma unroll
        for (int m = 0; m < 4; ++m) {
            #pragma unroll
            for (int rg = 0; rg < 4; ++rg) {
                const int x = m*16 + lg*4 + rg;
                const size_t vbase = ((size_t)((z*Hy + ygl)*Wx + x))*CHN;
                #pragma unroll
                for (int n = 0; n < 4; ++n) {
                    const int co = wn*64 + n*16 + lr;
                    float g = gelu_tanh(acc[m][n][rg] + bn[n]);
                    _Float16 h = (_Float16)g;
                    _Float16 l = (_Float16)(g - (float)h);
                    ohi[vbase + co] = __builtin_bit_cast(unsigned short, h);
                    olo[vbase + co] = __builtin_bit_cast(unsigned short, l);
                }
            }
        }
    } else {
        // detection head from registers: per-lane partial dots over its 4 cos
        float wl[4], wr0[4], wr1[4], wr2[4];
        #pragma unroll
        for (int n = 0; n < 4; ++n) {
            const int co = wn*64 + n*16 + lr;
            wl[n] = wlog[co];
            wr0[n] = wreg[co*3 + 0]; wr1[n] = wreg[co*3 + 1]; wr2[n] = wreg[co*3 + 2];
        }
        float p[4][16];
        #pragma unroll
        for (int c = 0; c < 4; ++c)
            #pragma unroll
            for (int xi = 0; xi < 16; ++xi) p[c][xi] = 0.f;
        #pragma unroll
        for (int m = 0; m < 4; ++m)
            #pragma unroll
            for (int rg = 0; rg < 4; ++rg) {
                const int xi = m*4 + rg;
                #pragma unroll
                for (int n = 0; n < 4; ++n) {
                    float g = gelu_tanh(acc[m][n][rg] + bn[n]);
                    p[0][xi] += g*wl[n];
                    p[1][xi] += g*wr0[n];
                    p[2][xi] += g*wr1[n];
                    p[3][xi] += g*wr2[n];
                }
            }
        #pragma unroll
        for (int st = 0; st < 4; ++st) {
            const int s = 1 << st;
            #pragma unroll
            for (int c = 0; c < 4; ++c)
                #pragma unroll
                for (int xi = 0; xi < 16; ++xi)
                    p[c][xi] += __shfl_xor(p[c][xi], s, 64);
        }
        __syncthreads();                 // stage buffer dead -> reuse as det
        float* det = (float*)sm;         // [2][64][4][4] = 8 KB
        if (lr == 0) {
            #pragma unroll
            for (int m = 0; m < 4; ++m)
                #pragma unroll
                for (int rg = 0; rg < 4; ++rg) {
                    const int x = m*16 + lg*4 + rg;
                    #pragma unroll
                    for (int c = 0; c < 4; ++c)
                        det[((yo*64 + x)*4 + c)*4 + wn] = p[c][m*4 + rg];
                }
        }
        __syncthreads();
        {
            const int yo2 = tid >> 8, x = (tid >> 2) & 63, chn = tid & 3;
            const float* dp = det + ((yo2*64 + x)*4 + chn)*4;
            float s = dp[0] + dp[1] + dp[2] + dp[3];
            const int ygl = y0 + yo2;
            const int vg = (z*Hy + ygl)*Wx + x;
            if (chn == 0) {
                float logit = s + blog[0];
                float score = 1.f/(1.f + expf(-logit));
                unsigned sb = f2sort(score);
                keys[vg] = ((unsigned long long)sb << 32)
                         | (unsigned long long)(0xFFFFFFFFu - (unsigned)vg);
                atomicAdd(&hist[sb >> 12], 1u);
            } else {
                float coord = (chn == 1) ? (float)z : (chn == 2) ? (float)ygl : (float)x;
                float loc = (coord + 0.5f)*4.0f + (s + breg[chn-1])*4.0f;
                locs[(size_t)vg*3 + (chn-1)] = loc;
            }
        }
    }
}

// --------------------------- selection / NMS tail ---------------------------
__global__ void zero_kernel(unsigned* __restrict__ hist, unsigned* __restrict__ counter) {
    int i = blockIdx.x*blockDim.x + threadIdx.x;
    if (i < (1 << 20)) hist[i] = 0u;
    if (i == 0) counter[0] = 0u;
}

__global__ __launch_bounds__(1024) void find_cut_kernel(const unsigned* __restrict__ hist,
                                                        unsigned* __restrict__ cutp) {
    __shared__ unsigned long long psum[1024];
    __shared__ unsigned h2[1024];
    __shared__ int sh_cb;
    __shared__ unsigned long long sh_acc;
    int t = threadIdx.x;
    unsigned long long s = 0;
    const unsigned* hp = hist + (size_t)t*1024;
    for (int b = 0; b < 1024; ++b) s += hp[b];
    psum[t] = s;
    __syncthreads();
    if (t == 0) {
        unsigned long long acc = 0; int cb = 0;
        for (int c = 1023; c >= 0; --c) {
            if (acc + psum[c] >= TOPK) { cb = c; break; }
            acc += psum[c];
        }
        sh_cb = cb; sh_acc = acc;
    }
    __syncthreads();
    int cb = sh_cb;
    h2[t] = hist[(size_t)cb*1024 + t];
    __syncthreads();
    if (t == 0) {
        unsigned long long acc = sh_acc; int cut = cb*1024;
        for (int b = 1023; b >= 0; --b) {
            acc += h2[b];
            if (acc >= TOPK) { cut = cb*1024 + b; break; }
        }
        cutp[0] = ((unsigned)cut) << 12;
    }
}

__global__ void compact_kernel(const unsigned long long* __restrict__ keys,
                               const unsigned* __restrict__ cutp,
                               unsigned* __restrict__ counter,
                               unsigned long long* __restrict__ cand) {
    int i = blockIdx.x*blockDim.x + threadIdx.x;
    unsigned thr = cutp[0];
    unsigned long long k = keys[i];
    if ((unsigned)(k >> 32) >= thr) {
        unsigned p = atomicAdd(counter, 1u);
        if (p < CAND_CAP) cand[p] = k;
    }
}

__global__ __launch_bounds__(512) void sort_nms_kernel(const unsigned* __restrict__ counter,
        const unsigned long long* __restrict__ cand,
        const float* __restrict__ locs, const int* __restrict__ mask,
        float* __restrict__ out) {
    __shared__ unsigned long long skey[CAND_CAP];   // 32 KB, later reused
    __shared__ float sscore[TOPK];
    __shared__ unsigned sidx[TOPK];
    __shared__ unsigned char keepf[TOPK];
    __shared__ unsigned char supf[TOPK];
    __shared__ int scanA[TOPK];
    int t = threadIdx.x;
    int M = (int)*counter; if (M > CAND_CAP) M = CAND_CAP;
    for (int i = t; i < CAND_CAP; i += 512) skey[i] = (i < M) ? cand[i] : 0ull;
    __syncthreads();
    for (int k = 2; k <= CAND_CAP; k <<= 1) {
        for (int j = k >> 1; j > 0; j >>= 1) {
            for (int i = t; i < CAND_CAP; i += 512) {
                int l = i ^ j;
                if (l > i) {
                    unsigned long long a = skey[i], bb = skey[l];
                    bool sw = ((i & k) == 0) ? (a < bb) : (a > bb);
                    if (sw) { skey[i] = bb; skey[l] = a; }
                }
            }
            __syncthreads();
        }
    }
    for (int i = t; i < TOPK; i += 512) {
        unsigned long long kk = skey[i];
        sscore[i] = sort2f((unsigned)(kk >> 32));
        sidx[i] = 0xFFFFFFFFu - (unsigned)(kk & 0xFFFFFFFFull);
        supf[i] = 0;
    }
    __syncthreads();
    float* sloc = (float*)skey;
    for (int i = t; i < TOPK; i += 512) {
        unsigned v = sidx[i];
        sloc[i*3+0] = locs[(size_t)v*3+0];
        sloc[i*3+1] = locs[(size_t)v*3+1];
        sloc[i*3+2] = locs[(size_t)v*3+2];
    }
    __syncthreads();
    for (int i = 0; i < TOPK; ++i) {
        bool kept = (supf[i] == 0) && (sscore[i] >= 0.2f);
        if (t == 0) keepf[i] = kept ? 1 : 0;
        if (kept) {
            float pz = sloc[i*3+0], py = sloc[i*3+1], px = sloc[i*3+2];
            for (int jj = t; jj < TOPK; jj += 512) {
                float az = sloc[jj*3+0]-pz, ay = sloc[jj*3+1]-py, ax = sloc[jj*3+2]-px;
                if (az*az + ay*ay + ax*ax < 64.0f) supf[jj] = 1;
            }
        }
        __syncthreads();
    }
    for (int i = t; i < TOPK; i += 512) scanA[i] = keepf[i];
    __syncthreads();
    int* sB = ((int*)skey) + TOPK*3;
    for (int off = 1; off < TOPK; off <<= 1) {
        for (int i = t; i < TOPK; i += 512) sB[i] = scanA[i] + ((i >= off) ? scanA[i-off] : 0);
        __syncthreads();
        for (int i = t; i < TOPK; i += 512) scanA[i] = sB[i];
        __syncthreads();
    }
    int nk = scanA[TOPK-1];
    for (int i = t; i < TOPK; i += 512) {
        bool kp = keepf[i] != 0;
        int slot = kp ? (scanA[i] - 1) : (nk + (i + 1 - scanA[i]) - 1);
        if (slot < MAXOUT) {
            float lz = sloc[i*3+0], ly = sloc[i*3+1], lx = sloc[i*3+2];
            float sc = kp ? sscore[i] : 0.f;
            int iz = (int)floorf(lz), iy = (int)floorf(ly), ix = (int)floorf(lx);
            int cz = min(max(iz,0),Dz*4-1), cy = min(max(iy,0),Hy*4-1), cx = min(max(ix,0),Wx*4-1);
            bool inr = (iz==cz) && (iy==cy) && (ix==cx);
            float osc = (inr && mask[((size_t)cz*(Hy*4) + cy)*(Wx*4) + cx] != 0) ? sc : 0.f;
            out[slot*4+0] = lz; out[slot*4+1] = ly; out[slot*4+2] = lx; out[slot*4+3] = osc;
        }
    }
}

extern "C" void kernel_launch(void* const* d_in, const int* in_sizes, int n_in,
                              void* d_out, int out_size, void* d_ws, size_t ws_size,
                              hipStream_t stream) {
    const float* feature = (const float*)d_in[0];
    const int*   mask    = (const int*)d_in[1];
    const float* w0   = (const float*)d_in[2];
    const float* b0   = (const float*)d_in[3];
    const float* w1   = (const float*)d_in[4];
    const float* b1   = (const float*)d_in[5];
    const float* wlog = (const float*)d_in[6];
    const float* blog = (const float*)d_in[7];
    const float* wreg = (const float*)d_in[8];
    const float* breg = (const float*)d_in[9];

    char* ws = (char*)d_ws;
    size_t off = 0;
    unsigned short* h1hi = (unsigned short*)(ws + off); off += (size_t)NVOX*CHN*2;  // 33.5 MB
    unsigned short* h1lo = (unsigned short*)(ws + off); off += (size_t)NVOX*CHN*2;  // 33.5 MB
    u16x8* wpk0 = (u16x8*)(ws + off);               off += (size_t)442368*16;       // 7.1 MB
    u16x8* wpk1 = (u16x8*)(ws + off);               off += (size_t)442368*16;       // 7.1 MB
    unsigned long long* keys = (unsigned long long*)(ws + off); off += (size_t)NVOX*8;
    float* locs = (float*)(ws + off);               off += (size_t)NVOX*3*4;
    unsigned* hist = (unsigned*)(ws + off);         off += (size_t)(1u<<20)*4;      // 4 MB
    unsigned* counter = (unsigned*)(ws + off);      off += 256;
    unsigned* cutp = counter + 1;
    unsigned long long* cand = (unsigned long long*)(ws + off); off += (size_t)CAND_CAP*8;
    if (ws_size < off) return;   // scratch too small: fail loudly (poison output)

    zero_kernel<<<4096, 256, 0, stream>>>(hist, counter);
    pack_w_kernel<<<1728, 256, 0, stream>>>(w0, w1, wpk0, wpk1);
    dim3 cgrid(Hy/2, Dz);
    conv_kernel<0><<<cgrid, 512, 0, stream>>>(feature, nullptr, nullptr, wpk0, b0,
                                              h1hi, h1lo,
                                              nullptr, nullptr, nullptr, nullptr,
                                              nullptr, nullptr, nullptr);
    conv_kernel<1><<<cgrid, 512, 0, stream>>>(nullptr, h1hi, h1lo, wpk1, b1,
                                              nullptr, nullptr,
                                              wlog, blog, wreg, breg,
                                              locs, keys, hist);
    find_cut_kernel<<<1, 1024, 0, stream>>>(hist, cutp);
    compact_kernel<<<NVOX/256, 256, 0, stream>>>(keys, cutp, counter, cand);
    sort_nms_kernel<<<1, 512, 0, stream>>>(counter, cand, locs, mask, (float*)d_out);
}

// Round 3
// 2141.161 us; speedup vs baseline: 3.2567x; 1.1122x over previous
//
#include <hip/hip_runtime.h>
#include <math.h>

#define Dz 16
#define Hy 64
#define Wx 64
#define CHN 256
#define NVOX (Dz*Hy*Wx)      // 65536
#define TOPK 2048
#define MAXOUT 256
#define CAND_CAP 4096

typedef __attribute__((ext_vector_type(8))) _Float16 h8;
typedef __attribute__((ext_vector_type(8))) unsigned short u16x8;
typedef __attribute__((ext_vector_type(4))) float f32x4;

__device__ __forceinline__ float gelu_tanh(float x) {
    return 0.5f*x*(1.0f + tanhf(0.7978845608028654f*(x + 0.044715f*x*x*x)));
}
__device__ __forceinline__ unsigned f2sort(float f) {
    unsigned u = __float_as_uint(f);
    return (u & 0x80000000u) ? ~u : (u | 0x80000000u);
}
__device__ __forceinline__ float sort2f(unsigned s) {
    unsigned u = (s & 0x80000000u) ? (s & 0x7fffffffu) : ~s;
    return __uint_as_float(u);
}

#define MFMA(d, a, b) d = __builtin_amdgcn_mfma_f32_16x16x32_f16(a, b, d, 0, 0, 0)

// ---------------------------------------------------------------------------
// Weight pre-pack: w[tap][k][co] f32 -> per-lane MFMA B-fragment order, f16
// hi/lo planes. Chunk (16B) = (((tap*8+kbg)*16 + ng)*2 + plane)*64 + lane,
// holding B[k = kbg*32 + (lane>>4)*8 + j][co = ng*16 + (lane&15)], j=0..7.
// ---------------------------------------------------------------------------
__global__ __launch_bounds__(256) void pack_w_kernel(const float* __restrict__ w0,
        const float* __restrict__ w1, u16x8* __restrict__ wpk0,
        u16x8* __restrict__ wpk1) {
    int id = blockIdx.x*256 + threadIdx.x;        // 442368 total
    int l = (id >= 221184) ? 1 : 0;
    int r = id - l*221184;
    int lane = r & 63, ng = (r >> 6) & 15, kbg = (r >> 10) & 7, t = r >> 13; // t 0..26
    const float* w = l ? w1 : w0;
    u16x8* dst = l ? wpk1 : wpk0;
    h8 hv = {0,0,0,0,0,0,0,0}, lv = {0,0,0,0,0,0,0,0};
    #pragma unroll
    for (int j = 0; j < 8; ++j) {
        int k = kbg*32 + (lane >> 4)*8 + j;
        int co = ng*16 + (lane & 15);
        float v = w[((size_t)t*CHN + k)*CHN + co];
        _Float16 h = (_Float16)v;
        hv[j] = h;
        lv[j] = (_Float16)(v - (float)h);
    }
    size_t base = (((size_t)(t*8 + kbg)*16 + ng)*2)*64 + lane;
    dst[base]      = __builtin_bit_cast(u16x8, hv);
    dst[base + 64] = __builtin_bit_cast(u16x8, lv);
}

// ---------------------------------------------------------------------------
// Conv layer as MFMA GEMM. Block = (z, y0..y0+1): M=128 voxels, N=256 cos.
// 512 threads = 8 waves: yo = w>>2, wn = w&3 (co 64-range). Wave tile 64x64.
// LDS: [plane2][iy4][row66][chunk8] of 16B f16 chunks, XOR-(r&7) swizzled.
// ---------------------------------------------------------------------------
template<int LAYER>
__global__ __launch_bounds__(512, 4) void conv_kernel(
        const float* __restrict__ fsrc,
        const unsigned short* __restrict__ hhi, const unsigned short* __restrict__ hlo,
        const u16x8* __restrict__ wpk, const float* __restrict__ bias,
        unsigned short* __restrict__ ohi, unsigned short* __restrict__ olo,
        const float* __restrict__ wlog, const float* __restrict__ blog,
        const float* __restrict__ wreg, const float* __restrict__ breg,
        float* __restrict__ locs, unsigned long long* __restrict__ keys,
        unsigned* __restrict__ hist) {
    __shared__ h8 sm[4224];                       // 67584 B
    const int tid = threadIdx.x;
    const int lane = tid & 63, w = tid >> 6;
    const int yo = w >> 2, wn = w & 3;
    const int lr = lane & 15, lg = lane >> 4;
    const int z = blockIdx.y, y0 = blockIdx.x*2;

    f32x4 acc[4][4];
    #pragma unroll
    for (int m = 0; m < 4; ++m)
        #pragma unroll
        for (int n = 0; n < 4; ++n) acc[m][n] = (f32x4){0.f,0.f,0.f,0.f};

    for (int dz = 0; dz < 3; ++dz) {
        const int zz = z + dz - 1;
        for (int kc = 0; kc < 4; ++kc) {
            __syncthreads();
            // ------------- stage 4 in-rows (hi/lo) for this (dz, kc) -------------
            if (LAYER == 0) {
                for (int cidx = tid; cidx < 2112; cidx += 512) {
                    int cd = cidx & 7;
                    int rr = cidx >> 3;
                    int r = rr % 66, iy = rr / 66;
                    int ygl = y0 - 1 + iy, xin = r - 1;
                    h8 hv = {0,0,0,0,0,0,0,0}, lv = {0,0,0,0,0,0,0,0};
                    if (((unsigned)zz < (unsigned)Dz) & ((unsigned)ygl < (unsigned)Hy)
                        & ((unsigned)xin < (unsigned)Wx)) {
                        const float* s = fsrc + ((size_t)((zz*Hy + ygl)*Wx + xin))*CHN
                                              + kc*64 + cd*8;
                        float4 t0 = *(const float4*)s;
                        float4 t1 = *(const float4*)(s + 4);
                        float vv[8] = {t0.x,t0.y,t0.z,t0.w,t1.x,t1.y,t1.z,t1.w};
                        #pragma unroll
                        for (int j = 0; j < 8; ++j) {
                            _Float16 h = (_Float16)vv[j];
                            hv[j] = h;
                            lv[j] = (_Float16)(vv[j] - (float)h);
                        }
                    }
                    int sl = cd ^ (r & 7);
                    sm[(iy*66 + r)*8 + sl] = hv;
                    sm[2112 + (iy*66 + r)*8 + sl] = lv;
                }
            } else {
                for (int cidx = tid; cidx < 4224; cidx += 512) {
                    int c = cidx & 7;
                    int rr = cidx >> 3;
                    int r = rr % 66, tt = rr / 66;     // tt = p*4+iy
                    int p = tt >> 2, iy = tt & 3;
                    int ygl = y0 - 1 + iy, xin = r - 1;
                    u16x8 v = {0,0,0,0,0,0,0,0};
                    if (((unsigned)zz < (unsigned)Dz) & ((unsigned)ygl < (unsigned)Hy)
                        & ((unsigned)xin < (unsigned)Wx)) {
                        const unsigned short* bp = p ? hlo : hhi;
                        v = *(const u16x8*)(bp + ((size_t)((zz*Hy + ygl)*Wx + xin))*CHN
                                               + kc*64 + (size_t)((c ^ (r & 7)))*8);
                    }
                    sm[cidx] = __builtin_bit_cast(h8, v);
                }
            }
            __syncthreads();
            // ------------- compute: 9 (dy,dx) taps x 2 kb -------------
            for (int dy = 0; dy < 3; ++dy) {
                const int iyA = yo + dy;
                const h8* As = sm + iyA*528;
                #pragma unroll
                for (int dx = 0; dx < 3; ++dx) {
                    const int tap = (dz*3 + dy)*3 + dx;
                    #pragma unroll
                    for (int kb = 0; kb < 2; ++kb) {
                        const int kbg = kc*2 + kb;
                        const u16x8* wb = wpk + ((size_t)(tap*8 + kbg)*32 + wn*8)*64 + lane;
                        h8 bh[4];
                        #pragma unroll
                        for (int n = 0; n < 4; ++n)
                            bh[n] = __builtin_bit_cast(h8, wb[(size_t)n*128]);
                        #pragma unroll
                        for (int m = 0; m < 4; ++m) {
                            const int r = m*16 + lr + dx;
                            const int sl = (kb*4 + lg) ^ (r & 7);
                            h8 ah = As[r*8 + sl];
                            h8 al = As[2112 + r*8 + sl];
                            #pragma unroll
                            for (int n = 0; n < 4; ++n) {
                                MFMA(acc[m][n], ah, bh[n]);
                                MFMA(acc[m][n], al, bh[n]);
                            }
                        }
                        h8 bl[4];
                        #pragma unroll
                        for (int n = 0; n < 4; ++n)
                            bl[n] = __builtin_bit_cast(h8, wb[(size_t)n*128 + 64]);
                        #pragma unroll
                        for (int m = 0; m < 4; ++m) {
                            const int r = m*16 + lr + dx;
                            const int sl = (kb*4 + lg) ^ (r & 7);
                            h8 ah = As[r*8 + sl];
                            #pragma unroll
                            for (int n = 0; n < 4; ++n) MFMA(acc[m][n], ah, bl[n]);
                        }
                    }
                }
            }
        }
    }

    // ------------------------------ epilogue ------------------------------
    float bn[4];
    #pragma unroll
    for (int n = 0; n < 4; ++n) bn[n] = bias[wn*64 + n*16 + lr];

    if (LAYER == 0) {
        const int ygl = y0 + yo;
        #pragma unroll
        for (int m = 0; m < 4; ++m) {
            #pragma unroll
            for (int rg = 0; rg < 4; ++rg) {
                const int x = m*16 + lg*4 + rg;
                const size_t vbase = ((size_t)((z*Hy + ygl)*Wx + x))*CHN;
                #pragma unroll
                for (int n = 0; n < 4; ++n) {
                    const int co = wn*64 + n*16 + lr;
                    float g = gelu_tanh(acc[m][n][rg] + bn[n]);
                    _Float16 h = (_Float16)g;
                    _Float16 l = (_Float16)(g - (float)h);
                    ohi[vbase + co] = __builtin_bit_cast(unsigned short, h);
                    olo[vbase + co] = __builtin_bit_cast(unsigned short, l);
                }
            }
        }
    } else {
        // detection head from registers: per-lane partial dots over its 4 cos
        float wl[4], wr0[4], wr1[4], wr2[4];
        #pragma unroll
        for (int n = 0; n < 4; ++n) {
            const int co = wn*64 + n*16 + lr;
            wl[n] = wlog[co];
            wr0[n] = wreg[co*3 + 0]; wr1[n] = wreg[co*3 + 1]; wr2[n] = wreg[co*3 + 2];
        }
        float p[4][16];
        #pragma unroll
        for (int c = 0; c < 4; ++c)
            #pragma unroll
            for (int xi = 0; xi < 16; ++xi) p[c][xi] = 0.f;
        #pragma unroll
        for (int m = 0; m < 4; ++m)
            #pragma unroll
            for (int rg = 0; rg < 4; ++rg) {
                const int xi = m*4 + rg;
                #pragma unroll
                for (int n = 0; n < 4; ++n) {
                    float g = gelu_tanh(acc[m][n][rg] + bn[n]);
                    p[0][xi] += g*wl[n];
                    p[1][xi] += g*wr0[n];
                    p[2][xi] += g*wr1[n];
                    p[3][xi] += g*wr2[n];
                }
            }
        #pragma unroll
        for (int st = 0; st < 4; ++st) {
            const int s = 1 << st;
            #pragma unroll
            for (int c = 0; c < 4; ++c)
                #pragma unroll
                for (int xi = 0; xi < 16; ++xi)
                    p[c][xi] += __shfl_xor(p[c][xi], s, 64);
        }
        __syncthreads();                 // stage buffer dead -> reuse as det
        float* det = (float*)sm;         // [2][64][4][4] = 8 KB
        if (lr == 0) {
            #pragma unroll
            for (int m = 0; m < 4; ++m)
                #pragma unroll
                for (int rg = 0; rg < 4; ++rg) {
                    const int x = m*16 + lg*4 + rg;
                    #pragma unroll
                    for (int c = 0; c < 4; ++c)
                        det[((yo*64 + x)*4 + c)*4 + wn] = p[c][m*4 + rg];
                }
        }
        __syncthreads();
        {
            const int yo2 = tid >> 8, x = (tid >> 2) & 63, chn = tid & 3;
            const float* dp = det + ((yo2*64 + x)*4 + chn)*4;
            float s = dp[0] + dp[1] + dp[2] + dp[3];
            const int ygl = y0 + yo2;
            const int vg = (z*Hy + ygl)*Wx + x;
            if (chn == 0) {
                float logit = s + blog[0];
                float score = 1.f/(1.f + expf(-logit));
                unsigned sb = f2sort(score);
                keys[vg] = ((unsigned long long)sb << 32)
                         | (unsigned long long)(0xFFFFFFFFu - (unsigned)vg);
                atomicAdd(&hist[sb >> 12], 1u);
            } else {
                float coord = (chn == 1) ? (float)z : (chn == 2) ? (float)ygl : (float)x;
                float loc = (coord + 0.5f)*4.0f + (s + breg[chn-1])*4.0f;
                locs[(size_t)vg*3 + (chn-1)] = loc;
            }
        }
    }
}

// --------------------------- selection / NMS tail ---------------------------
__global__ void zero_kernel(unsigned* __restrict__ hist, unsigned* __restrict__ counter) {
    int i = blockIdx.x*blockDim.x + threadIdx.x;
    if (i < (1 << 20)) hist[i] = 0u;
    if (i == 0) counter[0] = 0u;
}

__global__ __launch_bounds__(1024) void find_cut_kernel(const unsigned* __restrict__ hist,
                                                        unsigned* __restrict__ cutp) {
    __shared__ unsigned long long psum[1024];
    __shared__ unsigned h2[1024];
    __shared__ int sh_cb;
    __shared__ unsigned long long sh_acc;
    int t = threadIdx.x;
    unsigned long long s = 0;
    const unsigned* hp = hist + (size_t)t*1024;
    for (int b = 0; b < 1024; ++b) s += hp[b];
    psum[t] = s;
    __syncthreads();
    if (t == 0) {
        unsigned long long acc = 0; int cb = 0;
        for (int c = 1023; c >= 0; --c) {
            if (acc + psum[c] >= TOPK) { cb = c; break; }
            acc += psum[c];
        }
        sh_cb = cb; sh_acc = acc;
    }
    __syncthreads();
    int cb = sh_cb;
    h2[t] = hist[(size_t)cb*1024 + t];
    __syncthreads();
    if (t == 0) {
        unsigned long long acc = sh_acc; int cut = cb*1024;
        for (int b = 1023; b >= 0; --b) {
            acc += h2[b];
            if (acc >= TOPK) { cut = cb*1024 + b; break; }
        }
        cutp[0] = ((unsigned)cut) << 12;
    }
}

__global__ void compact_kernel(const unsigned long long* __restrict__ keys,
                               const unsigned* __restrict__ cutp,
                               unsigned* __restrict__ counter,
                               unsigned long long* __restrict__ cand) {
    int i = blockIdx.x*blockDim.x + threadIdx.x;
    unsigned thr = cutp[0];
    unsigned long long k = keys[i];
    if ((unsigned)(k >> 32) >= thr) {
        unsigned p = atomicAdd(counter, 1u);
        if (p < CAND_CAP) cand[p] = k;
    }
}

// Rank sort: keys unique -> rank = #{larger keys} is a permutation.
// 8 blocks x 512 threads, one candidate per thread; scatter planar sorted data.
__global__ __launch_bounds__(512) void rank_kernel(const unsigned* __restrict__ counter,
        const unsigned long long* __restrict__ cand, const float* __restrict__ locs,
        float* __restrict__ sscoreG, float* __restrict__ slzG,
        float* __restrict__ slyG, float* __restrict__ slxG) {
    __shared__ unsigned long long kbuf[CAND_CAP];   // 32 KB
    int t = threadIdx.x;
    int g = blockIdx.x*512 + t;
    int M = (int)*counter; if (M > CAND_CAP) M = CAND_CAP;
    for (int i = t; i < CAND_CAP; i += 512) kbuf[i] = (i < M) ? cand[i] : 0ull;
    __syncthreads();
    if (g >= M) return;
    unsigned long long mykey = kbuf[g];
    int rank = 0;
    for (int j = 0; j < M; ++j) rank += (kbuf[j] > mykey) ? 1 : 0;
    if (rank < TOPK) {
        unsigned idx = 0xFFFFFFFFu - (unsigned)(mykey & 0xFFFFFFFFull);
        sscoreG[rank] = sort2f((unsigned)(mykey >> 32));
        slzG[rank] = locs[(size_t)idx*3 + 0];
        slyG[rank] = locs[(size_t)idx*3 + 1];
        slxG[rank] = locs[(size_t)idx*3 + 2];
    }
}

// Greedy NMS: wave 0 runs the serial chain wave-synchronously (no barriers).
// Suppressed flags: 32 bits per lane (lane l owns candidates l*32..l*32+31).
// Coords in registers, statically indexed. Then 512-thread output epilogue.
__global__ __launch_bounds__(512) void nms_kernel(const float* __restrict__ sscoreG,
        const float* __restrict__ slzG, const float* __restrict__ slyG,
        const float* __restrict__ slxG, const int* __restrict__ mask,
        float* __restrict__ out) {
    __shared__ float ssc[TOPK], slz[TOPK], sly[TOPK], slx[TOPK];   // 32 KB
    __shared__ unsigned keepw[64];
    __shared__ int wpre[64];
    __shared__ int sh_nk;
    int t = threadIdx.x;
    for (int i = t; i < TOPK; i += 512) {
        ssc[i] = sscoreG[i]; slz[i] = slzG[i]; sly[i] = slyG[i]; slx[i] = slxG[i];
    }
    __syncthreads();
    if (t < 64) {
        const int l = t;
        float cz[32], cy[32], cx[32];
        #pragma unroll
        for (int j = 0; j < 32; ++j) {
            cz[j] = slz[l*32 + j]; cy[j] = sly[l*32 + j]; cx[j] = slx[l*32 + j];
        }
        int myok = 0;
        #pragma unroll
        for (int j = 0; j < 32; ++j) myok += (ssc[l*32 + j] >= 0.2f) ? 1 : 0;
        #pragma unroll
        for (int s = 1; s < 64; s <<= 1) myok += __shfl_xor(myok, s, 64);
        const int NS = myok;            // scores sorted desc -> ok set is a prefix
        unsigned supmask = 0u, keepmask = 0u;
        unsigned wcache = 0u; int wowner = -1;
        for (int i = 0; i < NS; ++i) {
            const int owner = i >> 5;
            if (owner != wowner) {      // refresh only on owner change or after a kept iter
                wcache = (unsigned)__shfl((int)supmask, owner, 64);
                wowner = owner;
            }
            if ((wcache >> (i & 31)) & 1u) continue;
            if (l == owner) keepmask |= 1u << (i & 31);
            const float pz = slz[i], py = sly[i], px = slx[i];
            if (l*32 + 31 > i) {        // lanes fully below i have nothing live to suppress
                #pragma unroll
                for (int j = 0; j < 32; ++j) {
                    float dz = cz[j]-pz, dy = cy[j]-py, dx = cx[j]-px;
                    float d2 = dz*dz + dy*dy + dx*dx;
                    if (d2 < 64.0f) supmask |= 1u << j;
                }
            }
            wowner = -1;                // suppression happened -> cached word stale
        }
        keepw[l] = keepmask;
    }
    __syncthreads();
    if (t < 64) {
        int p = 0;
        for (int j = 0; j < t; ++j) p += __popc(keepw[j]);
        wpre[t] = p;
        if (t == 63) sh_nk = p + __popc(keepw[63]);
    }
    __syncthreads();
    const int nk = sh_nk;
    for (int i = t; i < TOPK; i += 512) {
        unsigned w = keepw[i >> 5];
        bool kp = (w >> (i & 31)) & 1u;
        int rk = wpre[i >> 5] + __popc(w & ((1u << (i & 31)) - 1u));
        int slot = kp ? rk : (nk + (i - rk));
        if (slot < MAXOUT) {
            float lz = slz[i], ly = sly[i], lx = slx[i];
            float sc = kp ? ssc[i] : 0.f;
            int iz = (int)floorf(lz), iy = (int)floorf(ly), ix = (int)floorf(lx);
            int cz2 = min(max(iz,0),Dz*4-1), cy2 = min(max(iy,0),Hy*4-1), cx2 = min(max(ix,0),Wx*4-1);
            bool inr = (iz==cz2) && (iy==cy2) && (ix==cx2);
            float osc = (inr && mask[((size_t)cz2*(Hy*4) + cy2)*(Wx*4) + cx2] != 0) ? sc : 0.f;
            out[slot*4+0] = lz; out[slot*4+1] = ly; out[slot*4+2] = lx; out[slot*4+3] = osc;
        }
    }
}

extern "C" void kernel_launch(void* const* d_in, const int* in_sizes, int n_in,
                              void* d_out, int out_size, void* d_ws, size_t ws_size,
                              hipStream_t stream) {
    const float* feature = (const float*)d_in[0];
    const int*   mask    = (const int*)d_in[1];
    const float* w0   = (const float*)d_in[2];
    const float* b0   = (const float*)d_in[3];
    const float* w1   = (const float*)d_in[4];
    const float* b1   = (const float*)d_in[5];
    const float* wlog = (const float*)d_in[6];
    const float* blog = (const float*)d_in[7];
    const float* wreg = (const float*)d_in[8];
    const float* breg = (const float*)d_in[9];

    char* ws = (char*)d_ws;
    size_t off = 0;
    unsigned short* h1hi = (unsigned short*)(ws + off); off += (size_t)NVOX*CHN*2;  // 33.5 MB
    unsigned short* h1lo = (unsigned short*)(ws + off); off += (size_t)NVOX*CHN*2;  // 33.5 MB
    u16x8* wpk0 = (u16x8*)(ws + off);               off += (size_t)442368*16;       // 7.1 MB
    u16x8* wpk1 = (u16x8*)(ws + off);               off += (size_t)442368*16;       // 7.1 MB
    unsigned long long* keys = (unsigned long long*)(ws + off); off += (size_t)NVOX*8;
    float* locs = (float*)(ws + off);               off += (size_t)NVOX*3*4;
    unsigned* hist = (unsigned*)(ws + off);         off += (size_t)(1u<<20)*4;      // 4 MB
    unsigned* counter = (unsigned*)(ws + off);      off += 256;
    unsigned* cutp = counter + 1;
    unsigned long long* cand = (unsigned long long*)(ws + off); off += (size_t)CAND_CAP*8;
    float* sscoreG = (float*)(ws + off);            off += (size_t)TOPK*4;
    float* slzG = (float*)(ws + off);               off += (size_t)TOPK*4;
    float* slyG = (float*)(ws + off);               off += (size_t)TOPK*4;
    float* slxG = (float*)(ws + off);               off += (size_t)TOPK*4;
    if (ws_size < off) return;   // scratch too small: fail loudly (poison output)

    zero_kernel<<<4096, 256, 0, stream>>>(hist, counter);
    pack_w_kernel<<<1728, 256, 0, stream>>>(w0, w1, wpk0, wpk1);
    dim3 cgrid(Hy/2, Dz);
    conv_kernel<0><<<cgrid, 512, 0, stream>>>(feature, nullptr, nullptr, wpk0, b0,
                                              h1hi, h1lo,
                                              nullptr, nullptr, nullptr, nullptr,
                                              nullptr, nullptr, nullptr);
    conv_kernel<1><<<cgrid, 512, 0, stream>>>(nullptr, h1hi, h1lo, wpk1, b1,
                                              nullptr, nullptr,
                                              wlog, blog, wreg, breg,
                                              locs, keys, hist);
    find_cut_kernel<<<1, 1024, 0, stream>>>(hist, cutp);
    compact_kernel<<<NVOX/256, 256, 0, stream>>>(keys, cutp, counter, cand);
    rank_kernel<<<CAND_CAP/512, 512, 0, stream>>>(counter, cand, locs,
                                                  sscoreG, slzG, slyG, slxG);
    nms_kernel<<<1, 512, 0, stream>>>(sscoreG, slzG, slyG, slxG, mask, (float*)d_out);
}

// Round 4
// 1488.565 us; speedup vs baseline: 4.6845x; 1.4384x over previous
//
#include <hip/hip_runtime.h>
#include <math.h>

#define Dz 16
#define Hy 64
#define Wx 64
#define CHN 256
#define NVOX (Dz*Hy*Wx)      // 65536
#define TOPK 2048
#define MAXOUT 256
#define CAND_CAP 4096
#define NBCAP 16

typedef __attribute__((ext_vector_type(8))) _Float16 h8;
typedef __attribute__((ext_vector_type(8))) unsigned short u16x8;
typedef __attribute__((ext_vector_type(4))) float f32x4;

__device__ __forceinline__ float gelu_tanh(float x) {
    return 0.5f*x*(1.0f + tanhf(0.7978845608028654f*(x + 0.044715f*x*x*x)));
}
__device__ __forceinline__ unsigned f2sort(float f) {
    unsigned u = __float_as_uint(f);
    return (u & 0x80000000u) ? ~u : (u | 0x80000000u);
}
__device__ __forceinline__ float sort2f(unsigned s) {
    unsigned u = (s & 0x80000000u) ? (s & 0x7fffffffu) : ~s;
    return __uint_as_float(u);
}

#define MFMA(d, a, b) d = __builtin_amdgcn_mfma_f32_16x16x32_f16(a, b, d, 0, 0, 0)

// ---------------------------------------------------------------------------
// Weight pre-pack: w[tap][k][co] f32 -> per-lane MFMA B-fragment order, f16
// hi/lo planes. Chunk (16B) = (((tap*8+kbg)*16 + ng)*2 + plane)*64 + lane,
// holding B[k = kbg*32 + (lane>>4)*8 + j][co = ng*16 + (lane&15)], j=0..7.
// ---------------------------------------------------------------------------
__global__ __launch_bounds__(256) void pack_w_kernel(const float* __restrict__ w0,
        const float* __restrict__ w1, u16x8* __restrict__ wpk0,
        u16x8* __restrict__ wpk1) {
    int id = blockIdx.x*256 + threadIdx.x;        // 442368 total
    int l = (id >= 221184) ? 1 : 0;
    int r = id - l*221184;
    int lane = r & 63, ng = (r >> 6) & 15, kbg = (r >> 10) & 7, t = r >> 13; // t 0..26
    const float* w = l ? w1 : w0;
    u16x8* dst = l ? wpk1 : wpk0;
    h8 hv = {0,0,0,0,0,0,0,0}, lv = {0,0,0,0,0,0,0,0};
    #pragma unroll
    for (int j = 0; j < 8; ++j) {
        int k = kbg*32 + (lane >> 4)*8 + j;
        int co = ng*16 + (lane & 15);
        float v = w[((size_t)t*CHN + k)*CHN + co];
        _Float16 h = (_Float16)v;
        hv[j] = h;
        lv[j] = (_Float16)(v - (float)h);
    }
    size_t base = (((size_t)(t*8 + kbg)*16 + ng)*2)*64 + lane;
    dst[base]      = __builtin_bit_cast(u16x8, hv);
    dst[base + 64] = __builtin_bit_cast(u16x8, lv);
}

// ---------------------------------------------------------------------------
// Conv layer as MFMA GEMM. Block = (z, y0..y0+1): M=128 voxels, N=256 cos.
// 512 threads = 8 waves: yo = w>>2, wn = w&3 (co 64-range). Wave tile 64x64.
// LDS: [plane2][iy4][row66][chunk8] of 16B f16 chunks, XOR-(r&7) swizzled.
// ---------------------------------------------------------------------------
template<int LAYER>
__global__ __launch_bounds__(512, 4) void conv_kernel(
        const float* __restrict__ fsrc,
        const unsigned short* __restrict__ hhi, const unsigned short* __restrict__ hlo,
        const u16x8* __restrict__ wpk, const float* __restrict__ bias,
        unsigned short* __restrict__ ohi, unsigned short* __restrict__ olo,
        const float* __restrict__ wlog, const float* __restrict__ blog,
        const float* __restrict__ wreg, const float* __restrict__ breg,
        float* __restrict__ locs, unsigned long long* __restrict__ keys,
        unsigned* __restrict__ hist) {
    __shared__ h8 sm[4224];                       // 67584 B
    const int tid = threadIdx.x;
    const int lane = tid & 63, w = tid >> 6;
    const int yo = w >> 2, wn = w & 3;
    const int lr = lane & 15, lg = lane >> 4;
    const int z = blockIdx.y, y0 = blockIdx.x*2;

    f32x4 acc[4][4];
    #pragma unroll
    for (int m = 0; m < 4; ++m)
        #pragma unroll
        for (int n = 0; n < 4; ++n) acc[m][n] = (f32x4){0.f,0.f,0.f,0.f};

    for (int dz = 0; dz < 3; ++dz) {
        const int zz = z + dz - 1;
        for (int kc = 0; kc < 4; ++kc) {
            __syncthreads();
            // ------------- stage 4 in-rows (hi/lo) for this (dz, kc) -------------
            if (LAYER == 0) {
                for (int cidx = tid; cidx < 2112; cidx += 512) {
                    int cd = cidx & 7;
                    int rr = cidx >> 3;
                    int r = rr % 66, iy = rr / 66;
                    int ygl = y0 - 1 + iy, xin = r - 1;
                    h8 hv = {0,0,0,0,0,0,0,0}, lv = {0,0,0,0,0,0,0,0};
                    if (((unsigned)zz < (unsigned)Dz) & ((unsigned)ygl < (unsigned)Hy)
                        & ((unsigned)xin < (unsigned)Wx)) {
                        const float* s = fsrc + ((size_t)((zz*Hy + ygl)*Wx + xin))*CHN
                                              + kc*64 + cd*8;
                        float4 t0 = *(const float4*)s;
                        float4 t1 = *(const float4*)(s + 4);
                        float vv[8] = {t0.x,t0.y,t0.z,t0.w,t1.x,t1.y,t1.z,t1.w};
                        #pragma unroll
                        for (int j = 0; j < 8; ++j) {
                            _Float16 h = (_Float16)vv[j];
                            hv[j] = h;
                            lv[j] = (_Float16)(vv[j] - (float)h);
                        }
                    }
                    int sl = cd ^ (r & 7);
                    sm[(iy*66 + r)*8 + sl] = hv;
                    sm[2112 + (iy*66 + r)*8 + sl] = lv;
                }
            } else {
                for (int cidx = tid; cidx < 4224; cidx += 512) {
                    int c = cidx & 7;
                    int rr = cidx >> 3;
                    int r = rr % 66, tt = rr / 66;     // tt = p*4+iy
                    int p = tt >> 2, iy = tt & 3;
                    int ygl = y0 - 1 + iy, xin = r - 1;
                    u16x8 v = {0,0,0,0,0,0,0,0};
                    if (((unsigned)zz < (unsigned)Dz) & ((unsigned)ygl < (unsigned)Hy)
                        & ((unsigned)xin < (unsigned)Wx)) {
                        const unsigned short* bp = p ? hlo : hhi;
                        v = *(const u16x8*)(bp + ((size_t)((zz*Hy + ygl)*Wx + xin))*CHN
                                               + kc*64 + (size_t)((c ^ (r & 7)))*8);
                    }
                    sm[cidx] = __builtin_bit_cast(h8, v);
                }
            }
            __syncthreads();
            // ------------- compute: 9 (dy,dx) taps x 2 kb -------------
            for (int dy = 0; dy < 3; ++dy) {
                const int iyA = yo + dy;
                const h8* As = sm + iyA*528;
                #pragma unroll
                for (int dx = 0; dx < 3; ++dx) {
                    const int tap = (dz*3 + dy)*3 + dx;
                    #pragma unroll
                    for (int kb = 0; kb < 2; ++kb) {
                        const int kbg = kc*2 + kb;
                        const u16x8* wb = wpk + ((size_t)(tap*8 + kbg)*32 + wn*8)*64 + lane;
                        h8 bh[4];
                        #pragma unroll
                        for (int n = 0; n < 4; ++n)
                            bh[n] = __builtin_bit_cast(h8, wb[(size_t)n*128]);
                        #pragma unroll
                        for (int m = 0; m < 4; ++m) {
                            const int r = m*16 + lr + dx;
                            const int sl = (kb*4 + lg) ^ (r & 7);
                            h8 ah = As[r*8 + sl];
                            h8 al = As[2112 + r*8 + sl];
                            #pragma unroll
                            for (int n = 0; n < 4; ++n) {
                                MFMA(acc[m][n], ah, bh[n]);
                                MFMA(acc[m][n], al, bh[n]);
                            }
                        }
                        h8 bl[4];
                        #pragma unroll
                        for (int n = 0; n < 4; ++n)
                            bl[n] = __builtin_bit_cast(h8, wb[(size_t)n*128 + 64]);
                        #pragma unroll
                        for (int m = 0; m < 4; ++m) {
                            const int r = m*16 + lr + dx;
                            const int sl = (kb*4 + lg) ^ (r & 7);
                            h8 ah = As[r*8 + sl];
                            #pragma unroll
                            for (int n = 0; n < 4; ++n) MFMA(acc[m][n], ah, bl[n]);
                        }
                    }
                }
            }
        }
    }

    // ------------------------------ epilogue ------------------------------
    float bn[4];
    #pragma unroll
    for (int n = 0; n < 4; ++n) bn[n] = bias[wn*64 + n*16 + lr];

    if (LAYER == 0) {
        const int ygl = y0 + yo;
        #pragma unroll
        for (int m = 0; m < 4; ++m) {
            #pragma unroll
            for (int rg = 0; rg < 4; ++rg) {
                const int x = m*16 + lg*4 + rg;
                const size_t vbase = ((size_t)((z*Hy + ygl)*Wx + x))*CHN;
                #pragma unroll
                for (int n = 0; n < 4; ++n) {
                    const int co = wn*64 + n*16 + lr;
                    float g = gelu_tanh(acc[m][n][rg] + bn[n]);
                    _Float16 h = (_Float16)g;
                    _Float16 l = (_Float16)(g - (float)h);
                    ohi[vbase + co] = __builtin_bit_cast(unsigned short, h);
                    olo[vbase + co] = __builtin_bit_cast(unsigned short, l);
                }
            }
        }
    } else {
        // detection head from registers: per-lane partial dots over its 4 cos
        float wl[4], wr0[4], wr1[4], wr2[4];
        #pragma unroll
        for (int n = 0; n < 4; ++n) {
            const int co = wn*64 + n*16 + lr;
            wl[n] = wlog[co];
            wr0[n] = wreg[co*3 + 0]; wr1[n] = wreg[co*3 + 1]; wr2[n] = wreg[co*3 + 2];
        }
        float p[4][16];
        #pragma unroll
        for (int c = 0; c < 4; ++c)
            #pragma unroll
            for (int xi = 0; xi < 16; ++xi) p[c][xi] = 0.f;
        #pragma unroll
        for (int m = 0; m < 4; ++m)
            #pragma unroll
            for (int rg = 0; rg < 4; ++rg) {
                const int xi = m*4 + rg;
                #pragma unroll
                for (int n = 0; n < 4; ++n) {
                    float g = gelu_tanh(acc[m][n][rg] + bn[n]);
                    p[0][xi] += g*wl[n];
                    p[1][xi] += g*wr0[n];
                    p[2][xi] += g*wr1[n];
                    p[3][xi] += g*wr2[n];
                }
            }
        #pragma unroll
        for (int st = 0; st < 4; ++st) {
            const int s = 1 << st;
            #pragma unroll
            for (int c = 0; c < 4; ++c)
                #pragma unroll
                for (int xi = 0; xi < 16; ++xi)
                    p[c][xi] += __shfl_xor(p[c][xi], s, 64);
        }
        __syncthreads();                 // stage buffer dead -> reuse as det
        float* det = (float*)sm;         // [2][64][4][4] = 8 KB
        if (lr == 0) {
            #pragma unroll
            for (int m = 0; m < 4; ++m)
                #pragma unroll
                for (int rg = 0; rg < 4; ++rg) {
                    const int x = m*16 + lg*4 + rg;
                    #pragma unroll
                    for (int c = 0; c < 4; ++c)
                        det[((yo*64 + x)*4 + c)*4 + wn] = p[c][m*4 + rg];
                }
        }
        __syncthreads();
        {
            const int yo2 = tid >> 8, x = (tid >> 2) & 63, chn = tid & 3;
            const float* dp = det + ((yo2*64 + x)*4 + chn)*4;
            float s = dp[0] + dp[1] + dp[2] + dp[3];
            const int ygl = y0 + yo2;
            const int vg = (z*Hy + ygl)*Wx + x;
            if (chn == 0) {
                float logit = s + blog[0];
                float score = 1.f/(1.f + expf(-logit));
                unsigned sb = f2sort(score);
                keys[vg] = ((unsigned long long)sb << 32)
                         | (unsigned long long)(0xFFFFFFFFu - (unsigned)vg);
                atomicAdd(&hist[sb >> 12], 1u);
            } else {
                float coord = (chn == 1) ? (float)z : (chn == 2) ? (float)ygl : (float)x;
                float loc = (coord + 0.5f)*4.0f + (s + breg[chn-1])*4.0f;
                locs[(size_t)vg*3 + (chn-1)] = loc;
            }
        }
    }
}

// --------------------------- selection / NMS tail ---------------------------
__global__ void zero_kernel(unsigned* __restrict__ hist, unsigned* __restrict__ counter) {
    int i = blockIdx.x*blockDim.x + threadIdx.x;
    if (i < (1 << 20)) hist[i] = 0u;
    if (i == 0) counter[0] = 0u;
}

__global__ __launch_bounds__(1024) void find_cut_kernel(const unsigned* __restrict__ hist,
                                                        unsigned* __restrict__ cutp) {
    __shared__ unsigned long long psum[1024];
    __shared__ unsigned h2[1024];
    __shared__ int sh_cb;
    __shared__ unsigned long long sh_acc;
    int t = threadIdx.x;
    unsigned long long s = 0;
    const unsigned* hp = hist + (size_t)t*1024;
    for (int b = 0; b < 1024; ++b) s += hp[b];
    psum[t] = s;
    __syncthreads();
    if (t == 0) {
        unsigned long long acc = 0; int cb = 0;
        for (int c = 1023; c >= 0; --c) {
            if (acc + psum[c] >= TOPK) { cb = c; break; }
            acc += psum[c];
        }
        sh_cb = cb; sh_acc = acc;
    }
    __syncthreads();
    int cb = sh_cb;
    h2[t] = hist[(size_t)cb*1024 + t];
    __syncthreads();
    if (t == 0) {
        unsigned long long acc = sh_acc; int cut = cb*1024;
        for (int b = 1023; b >= 0; --b) {
            acc += h2[b];
            if (acc >= TOPK) { cut = cb*1024 + b; break; }
        }
        cutp[0] = ((unsigned)cut) << 12;
    }
}

__global__ void compact_kernel(const unsigned long long* __restrict__ keys,
                               const unsigned* __restrict__ cutp,
                               unsigned* __restrict__ counter,
                               unsigned long long* __restrict__ cand) {
    int i = blockIdx.x*blockDim.x + threadIdx.x;
    unsigned thr = cutp[0];
    unsigned long long k = keys[i];
    if ((unsigned)(k >> 32) >= thr) {
        unsigned p = atomicAdd(counter, 1u);
        if (p < CAND_CAP) cand[p] = k;
    }
}

// Rank sort: keys unique -> rank = #{larger keys} is a permutation.
// 8 blocks x 512 threads, one candidate per thread; scatter planar sorted data.
__global__ __launch_bounds__(512) void rank_kernel(const unsigned* __restrict__ counter,
        const unsigned long long* __restrict__ cand, const float* __restrict__ locs,
        float* __restrict__ sscoreG, float* __restrict__ slzG,
        float* __restrict__ slyG, float* __restrict__ slxG) {
    __shared__ unsigned long long kbuf[CAND_CAP];   // 32 KB
    int t = threadIdx.x;
    int g = blockIdx.x*512 + t;
    int M = (int)*counter; if (M > CAND_CAP) M = CAND_CAP;
    for (int i = t; i < CAND_CAP; i += 512) kbuf[i] = (i < M) ? cand[i] : 0ull;
    __syncthreads();
    if (g >= M) return;
    unsigned long long mykey = kbuf[g];
    int rank = 0;
    for (int j = 0; j < M; ++j) rank += (kbuf[j] > mykey) ? 1 : 0;
    if (rank < TOPK) {
        unsigned idx = 0xFFFFFFFFu - (unsigned)(mykey & 0xFFFFFFFFull);
        sscoreG[rank] = sort2f((unsigned)(mykey >> 32));
        slzG[rank] = locs[(size_t)idx*3 + 0];
        slyG[rank] = locs[(size_t)idx*3 + 1];
        slxG[rank] = locs[(size_t)idx*3 + 2];
    }
}

// Neighbor lists: for each sorted candidate, all others within NMS radius.
// 8 blocks x 256 threads, one candidate per thread, full 2048 sweep vs LDS.
__global__ __launch_bounds__(256) void nbr_kernel(const float* __restrict__ slzG,
        const float* __restrict__ slyG, const float* __restrict__ slxG,
        unsigned short* __restrict__ nbidx, unsigned char* __restrict__ nbcnt) {
    __shared__ float bz[TOPK], by[TOPK], bx[TOPK];   // 24 KB
    int t = threadIdx.x;
    int g = blockIdx.x*256 + t;
    for (int i = t; i < TOPK; i += 256) { bz[i]=slzG[i]; by[i]=slyG[i]; bx[i]=slxG[i]; }
    __syncthreads();
    float myz = bz[g], myy = by[g], myx = bx[g];
    int cnt = 0;
    for (int j = 0; j < TOPK; ++j) {
        float dz = bz[j]-myz, dy = by[j]-myy, dx = bx[j]-myx;
        float d2 = dz*dz + dy*dy + dx*dx;
        if (d2 < 64.0f && j != g) {
            if (cnt < NBCAP) nbidx[(size_t)g*NBCAP + cnt] = (unsigned short)j;
            cnt++;
        }
    }
    nbcnt[g] = (unsigned char)min(cnt, 255);
}

// Greedy NMS via neighbor lists, wave-synchronous, early-terminating at 256
// keeps (later keep flags provably can't affect the top-256 output).
__global__ __launch_bounds__(512) void nms_kernel(const float* __restrict__ sscoreG,
        const float* __restrict__ slzG, const float* __restrict__ slyG,
        const float* __restrict__ slxG, const unsigned short* __restrict__ nbidx,
        const unsigned char* __restrict__ nbcnt, const int* __restrict__ mask,
        float* __restrict__ out) {
    __shared__ float ssc[TOPK], slz[TOPK], sly[TOPK], slx[TOPK];   // 32 KB
    __shared__ unsigned short snb[TOPK*NBCAP];                      // 64 KB
    __shared__ unsigned char scnt[TOPK];                            // 2 KB
    __shared__ unsigned char supf[TOPK];                            // 2 KB
    __shared__ unsigned char keepB[TOPK];                           // 2 KB
    __shared__ unsigned keepw[64];
    __shared__ int wpre[64];
    __shared__ int sh_nk;
    int t = threadIdx.x;
    for (int i = t; i < TOPK; i += 512) {
        ssc[i] = sscoreG[i]; slz[i] = slzG[i]; sly[i] = slyG[i]; slx[i] = slxG[i];
        scnt[i] = nbcnt[i]; supf[i] = 0; keepB[i] = 0;
    }
    for (int i = t; i < TOPK*NBCAP/8; i += 512)
        ((uint4*)snb)[i] = ((const uint4*)nbidx)[i];
    __syncthreads();
    if (t < 64) {
        const int l = t;
        // register coord cache for the (rare) overflow fallback
        float cz[32], cy[32], cx[32];
        #pragma unroll
        for (int j = 0; j < 32; ++j) {
            cz[j] = slz[l*32 + j]; cy[j] = sly[l*32 + j]; cx[j] = slx[l*32 + j];
        }
        int keeps = 0;
        for (int i = 0; i < TOPK; ++i) {
            bool kept = (supf[i] == 0) && (ssc[i] >= 0.2f);
            if (kept) {
                if (l == 0) keepB[i] = 1;
                ++keeps;
                const int cnt = scnt[i];
                if (cnt <= NBCAP) {
                    if (l < cnt) supf[snb[i*NBCAP + l]] = 1;
                } else {
                    const float pz = slz[i], py = sly[i], px = slx[i];
                    #pragma unroll
                    for (int j = 0; j < 32; ++j) {
                        float dz = cz[j]-pz, dy = cy[j]-py, dx = cx[j]-px;
                        if (dz*dz + dy*dy + dx*dx < 64.0f) supf[l*32 + j] = 1;
                    }
                }
                asm volatile("s_waitcnt lgkmcnt(0)" ::: "memory");
                if (keeps >= MAXOUT) break;
            }
        }
    }
    __syncthreads();
    if (t < 64) {
        unsigned wmask = 0u;
        for (int j = 0; j < 32; ++j) wmask |= (keepB[t*32 + j] ? 1u : 0u) << j;
        keepw[t] = wmask;
    }
    __syncthreads();
    if (t < 64) {
        int p = 0;
        for (int j = 0; j < t; ++j) p += __popc(keepw[j]);
        wpre[t] = p;
        if (t == 63) sh_nk = p + __popc(keepw[63]);
    }
    __syncthreads();
    const int nk = sh_nk;
    for (int i = t; i < TOPK; i += 512) {
        unsigned w = keepw[i >> 5];
        bool kp = (w >> (i & 31)) & 1u;
        int rk = wpre[i >> 5] + __popc(w & ((1u << (i & 31)) - 1u));
        int slot = kp ? rk : (nk + (i - rk));
        if (slot < MAXOUT) {
            float lz = slz[i], ly = sly[i], lx = slx[i];
            float sc = kp ? ssc[i] : 0.f;
            int iz = (int)floorf(lz), iy = (int)floorf(ly), ix = (int)floorf(lx);
            int cz2 = min(max(iz,0),Dz*4-1), cy2 = min(max(iy,0),Hy*4-1), cx2 = min(max(ix,0),Wx*4-1);
            bool inr = (iz==cz2) && (iy==cy2) && (ix==cx2);
            float osc = (inr && mask[((size_t)cz2*(Hy*4) + cy2)*(Wx*4) + cx2] != 0) ? sc : 0.f;
            out[slot*4+0] = lz; out[slot*4+1] = ly; out[slot*4+2] = lx; out[slot*4+3] = osc;
        }
    }
}

extern "C" void kernel_launch(void* const* d_in, const int* in_sizes, int n_in,
                              void* d_out, int out_size, void* d_ws, size_t ws_size,
                              hipStream_t stream) {
    const float* feature = (const float*)d_in[0];
    const int*   mask    = (const int*)d_in[1];
    const float* w0   = (const float*)d_in[2];
    const float* b0   = (const float*)d_in[3];
    const float* w1   = (const float*)d_in[4];
    const float* b1   = (const float*)d_in[5];
    const float* wlog = (const float*)d_in[6];
    const float* blog = (const float*)d_in[7];
    const float* wreg = (const float*)d_in[8];
    const float* breg = (const float*)d_in[9];

    char* ws = (char*)d_ws;
    size_t off = 0;
    unsigned short* h1hi = (unsigned short*)(ws + off); off += (size_t)NVOX*CHN*2;  // 33.5 MB
    unsigned short* h1lo = (unsigned short*)(ws + off); off += (size_t)NVOX*CHN*2;  // 33.5 MB
    u16x8* wpk0 = (u16x8*)(ws + off);               off += (size_t)442368*16;       // 7.1 MB
    u16x8* wpk1 = (u16x8*)(ws + off);               off += (size_t)442368*16;       // 7.1 MB
    unsigned long long* keys = (unsigned long long*)(ws + off); off += (size_t)NVOX*8;
    float* locs = (float*)(ws + off);               off += (size_t)NVOX*3*4;
    unsigned* hist = (unsigned*)(ws + off);         off += (size_t)(1u<<20)*4;      // 4 MB
    unsigned* counter = (unsigned*)(ws + off);      off += 256;
    unsigned* cutp = counter + 1;
    unsigned long long* cand = (unsigned long long*)(ws + off); off += (size_t)CAND_CAP*8;
    float* sscoreG = (float*)(ws + off);            off += (size_t)TOPK*4;
    float* slzG = (float*)(ws + off);               off += (size_t)TOPK*4;
    float* slyG = (float*)(ws + off);               off += (size_t)TOPK*4;
    float* slxG = (float*)(ws + off);               off += (size_t)TOPK*4;
    unsigned short* nbidx = (unsigned short*)(ws + off); off += (size_t)TOPK*NBCAP*2;
    unsigned char* nbcnt = (unsigned char*)(ws + off);   off += (size_t)TOPK;
    if (ws_size < off) return;   // scratch too small: fail loudly (poison output)

    zero_kernel<<<4096, 256, 0, stream>>>(hist, counter);
    pack_w_kernel<<<1728, 256, 0, stream>>>(w0, w1, wpk0, wpk1);
    dim3 cgrid(Hy/2, Dz);
    conv_kernel<0><<<cgrid, 512, 0, stream>>>(feature, nullptr, nullptr, wpk0, b0,
                                              h1hi, h1lo,
                                              nullptr, nullptr, nullptr, nullptr,
                                              nullptr, nullptr, nullptr);
    conv_kernel<1><<<cgrid, 512, 0, stream>>>(nullptr, h1hi, h1lo, wpk1, b1,
                                              nullptr, nullptr,
                                              wlog, blog, wreg, breg,
                                              locs, keys, hist);
    find_cut_kernel<<<1, 1024, 0, stream>>>(hist, cutp);
    compact_kernel<<<NVOX/256, 256, 0, stream>>>(keys, cutp, counter, cand);
    rank_kernel<<<CAND_CAP/512, 512, 0, stream>>>(counter, cand, locs,
                                                  sscoreG, slzG, slyG, slxG);
    nbr_kernel<<<TOPK/256, 256, 0, stream>>>(slzG, slyG, slxG, nbidx, nbcnt);
    nms_kernel<<<1, 512, 0, stream>>>(sscoreG, slzG, slyG, slxG, nbidx, nbcnt,
                                      mask, (float*)d_out);
}